// Round 7
// baseline (298.759 us; speedup 1.0000x reference)
//
#include <hip/hip_runtime.h>

typedef float v4f __attribute__((ext_vector_type(4)));

namespace {
constexpr int B_     = 8;
constexpr int NT_    = 256;
constexpr int NX_    = 256;
constexpr int NREC_  = 64;
constexpr int PIECES = 16;             // 128 blocks
constexpr int IROWS  = 16;             // interior rows per strip
constexpr int G      = 16;             // ghost width = steps per round
constexpr int ROUNDS = NT_ / G;        // 16 (15 exchanges)
constexpr int NB     = (IROWS + 2 * G) / 4;  // bands per block = 12
constexpr int NTHR   = NB * 64;        // 768 threads
constexpr int NBLK   = B_ * PIECES;    // 128 blocks
constexpr float DT2  = 1e-6f;          // DT*DT
constexpr float KLAP = 1e-8f;          // DT*DT/(DH*DH)
constexpr size_t FLAGS_BYTES = 4096;
constexpr int RCAP = 6;
} // namespace

// lane i <- lane i-1 (shfl_up 1). Lane 0 gets 0.0f (bound_ctrl) -- masked by cf=0.
__device__ __forceinline__ float dpp_shr1(float v) {
    return __int_as_float(__builtin_amdgcn_update_dpp(
        0, __float_as_int(v), 0x138 /*WAVE_SHR1*/, 0xF, 0xF, true));
}
// lane i <- lane i+1 (shfl_down 1). Lane 63 gets 0.0f -- masked by cf=0.
__device__ __forceinline__ float dpp_shl1(float v) {
    return __int_as_float(__builtin_amdgcn_update_dpp(
        0, __float_as_int(v), 0x130 /*WAVE_SHL1*/, 0xF, 0xF, true));
}

// R10: fence-free cross-block exchange via sc0 sc1 (system-coherent; bypasses
// the non-coherent per-XCD L2s). R13: trapezoid band cutoffs (bit-identical).
// R14: SKEW-SYNC -- the per-step __syncthreads phase-serialized the LDS pipe
// (write burst | barrier | read burst + 120cy latency | compute ~= 925cy/step).
// Bands depend only on band+-1, so replace the barrier with a per-band LDS
// progress protocol: poll prog[band+-1] >= t (acquire), read halo pub[t%3],
// compute, publish pub[(t+1)%3], release prog=t+1. THREE parity slots make the
// WAR safe with the single pre-compute poll (prog[nbr]>=t ==> nbr done reading
// level t-2). Dead trapezoid bands jump prog to round-end (no deadlock); the
// freshness pattern is identical to R13 -> absmax stays bit-identical.
__device__ __forceinline__ void store_v4_sys(float* p, v4f v) {
    asm volatile("global_store_dwordx4 %0, %1, off sc0 sc1"
                 :: "v"(p), "v"(v) : "memory");
}
__device__ __forceinline__ v4f load_v4_sys(const float* p) {
    v4f r;
    asm volatile("global_load_dwordx4 %0, %1, off sc0 sc1"
                 : "=v"(r) : "v"(p) : "memory");
    return r;
}

extern "C" __global__
__attribute__((amdgpu_flat_work_group_size(NTHR, NTHR), amdgpu_waves_per_eu(4, 4)))
void wave_reg_kernel(const float* __restrict__ x,
                     const float* __restrict__ vp,
                     const int* __restrict__ src_loc,
                     const int* __restrict__ rec_loc,
                     float* __restrict__ out,
                     int* __restrict__ flags,   // [128] monotone round counters
                     float* __restrict__ gbuf)  // [par2][128][lvl2][16][256]
{
    __shared__ float pub[3][2][NB][256];   // 73.7 KB: [slot t%3][top/bot][band][col]
    __shared__ int   prog[NB];             // per-band published level (monotone)
    __shared__ float wav[NT_];             // 1 KB wavelet
    __shared__ float recbuf[G][NREC_];     // 4 KB receiver staging (per round)
    __shared__ unsigned char recown[NREC_];// per-rec ownership of this block

    const int bid  = blockIdx.x;
    const int b    = bid & 7;
    const int p    = bid >> 3;             // 0..15
    const int blk  = b * PIECES + p;
    const int tid  = threadIdx.x;
    const int band = tid >> 6;             // wave id 0..11 -> 4 ext rows
    const int lane = tid & 63;
    const int c0   = lane << 2;            // first owned col (0..252)
    const int grt  = p * IROWS - G + (band << 2);  // global row of owned row 0

    // trapezoid cutoff (R13, bit-identical-proven): compute step k iff k<=cut
    const int cut = (band < 4) ? ((band << 2) + 3)
                  : ((band < 8) ? G : (47 - (band << 2)));

    if (tid < NT_) wav[tid] = x[b * NT_ + tid];
    if (tid < NREC_) {
        int rz = rec_loc[(b * NREC_ + tid) * 2 + 0];
        recown[tid] = (rz >= p * IROWS && rz < p * IROWS + IROWS) ? 1 : 0;
    }

    // cf = vp^2*DT^2/DH^2, zeroed at Dirichlet boundary + out-of-domain rows.
    // cf2 = 2 - 4*cf: hn = cf*((N+S)+(E+W)) + (cf2*C - P)
    v4f cf[4], cf2[4];
#pragma unroll
    for (int i = 0; i < 4; ++i) {
        int gr = grt + i;
        int crow = gr < 0 ? 0 : (gr > 255 ? 255 : gr);
        bool rowok = (gr >= 1) && (gr <= 254);
        v4f vv = *(const v4f*)&vp[crow * NX_ + c0];
        float cc[4];
#pragma unroll
        for (int k = 0; k < 4; ++k) {
            int col = c0 + k;
            float vk = (k == 0) ? vv.x : (k == 1) ? vv.y : (k == 2) ? vv.z : vv.w;
            cc[k] = (rowok && col >= 1 && col <= 254) ? vk * vk * KLAP : 0.f;
        }
        cf[i].x = cc[0]; cf[i].y = cc[1]; cf[i].z = cc[2]; cf[i].w = cc[3];
        cf2[i].x = 2.f - 4.f * cc[0]; cf2[i].y = 2.f - 4.f * cc[1];
        cf2[i].z = 2.f - 4.f * cc[2]; cf2[i].w = 2.f - 4.f * cc[3];
    }

    // source ownership (ghost rows included: ghost evolution must replay it)
    const int sz = src_loc[b * 2 + 0], sx = src_loc[b * 2 + 1];
    const int si = sz - grt;               // 0..3 if owned row
    const int sj = sx - c0;                // 0..3 if owned col
    const bool has_src = ((unsigned)si < 4u) && ((unsigned)sj < 4u);
    const bool wave_has_src = __any(has_src);

    // receiver slots: interior owner only (unique writer). pk=(r<<4)|(i<<2)|j
    int rs[RCAP]; int rcnt = 0;
#pragma unroll 1
    for (int r = 0; r < NREC_; ++r) {
        int rz = rec_loc[(b * NREC_ + r) * 2 + 0];
        int rx = rec_loc[(b * NREC_ + r) * 2 + 1];
        int i = rz - grt, j = rx - c0;
        if (rz >= p * IROWS && rz < p * IROWS + IROWS &&
            (unsigned)i < 4u && (unsigned)j < 4u) {
            if (rcnt < RCAP) rs[rcnt] = (r << 4) | (i << 2) | j;
            ++rcnt;
        }
    }
    if (rcnt > RCAP) rcnt = RCAP;
    const bool wave_has_rec = __any(rcnt > 0);
    float* outb = out + (size_t)b * NT_ * NREC_;

    v4f A[4], Bv[4];
    {
        v4f z = {0.f, 0.f, 0.f, 0.f};
#pragma unroll
        for (int i = 0; i < 4; ++i) { A[i] = z; Bv[i] = z; }
    }

    // initial publish: level 0 (zeros) into slot 0; prog = 0
    *(v4f*)&pub[0][0][band][c0] = A[0];
    *(v4f*)&pub[0][1][band][c0] = A[3];
    if (lane == 0) prog[band] = 0;
    __syncthreads();

    // gbuf slab pointer: [par][blk][lvl][row][col]; interior = the slab.
    auto gptr = [&](int e, int bk, int lvl, int rr) -> float* {
        return gbuf + ((((size_t)(e & 1) * NBLK + bk) * 2 + lvl) * 16 + rr) * 256;
    };

// one stencil row: reads C[I], P[I] (old), writes P[I]. Literal I only (rule #20).
#define ROW(I, NV, SV) do {                                                   \
    float wv = dpp_shr1(C[I].w);   /* col c0-1 (lane0 -> 0: cf=0 masks) */    \
    float ev = dpp_shl1(C[I].x);   /* col c0+4 (lane63 -> 0: cf=0 masks) */   \
    v4f hn;                                                                   \
    { float sm = ((NV).x + (SV).x) + (wv     + C[I].y);                       \
      hn.x = fmaf(cf[I].x, sm, fmaf(cf2[I].x, C[I].x, -P[I].x)); }            \
    { float sm = ((NV).y + (SV).y) + (C[I].x + C[I].z);                       \
      hn.y = fmaf(cf[I].y, sm, fmaf(cf2[I].y, C[I].y, -P[I].y)); }            \
    { float sm = ((NV).z + (SV).z) + (C[I].y + C[I].w);                       \
      hn.z = fmaf(cf[I].z, sm, fmaf(cf2[I].z, C[I].z, -P[I].z)); }            \
    { float sm = ((NV).w + (SV).w) + (C[I].z + ev);                           \
      hn.w = fmaf(cf[I].w, sm, fmaf(cf2[I].w, C[I].w, -P[I].w)); }            \
    P[I] = hn;                                                                \
} while (0)

    // one step: C = level t (in pub slot t%3==s3), computes level t+1 into P,
    // publishes into slot (t+1)%3, releases prog = t+1 (or round-end if dying).
    auto step = [&](v4f (&C)[4], v4f (&P)[4], int t, int s3) {
        const int k = (t & (G - 1)) + 1;       // in-round step 1..16
        if (k > cut) return;                   // dead: prog already jumped
        const int nxt = (s3 == 2) ? 0 : s3 + 1;
        // poll: neighbors must have PUBLISHED level t (acquire orders the
        // subsequent pub reads behind the neighbor's release)
        if (band > 0)
            while (__hip_atomic_load(&prog[band - 1], __ATOMIC_ACQUIRE,
                                     __HIP_MEMORY_SCOPE_WORKGROUP) < t)
                __builtin_amdgcn_s_sleep(1);
        if (band < NB - 1)
            while (__hip_atomic_load(&prog[band + 1], __ATOMIC_ACQUIRE,
                                     __HIP_MEMORY_SCOPE_WORKGROUP) < t)
                __builtin_amdgcn_s_sleep(1);
        v4f nn, ss;
        if (band > 0)      nn = *(const v4f*)&pub[s3][1][band - 1][c0];
        else               { nn.x = 0.f; nn.y = 0.f; nn.z = 0.f; nn.w = 0.f; }
        if (band < NB - 1) ss = *(const v4f*)&pub[s3][0][band + 1][c0];
        else               { ss.x = 0.f; ss.y = 0.f; ss.z = 0.f; ss.w = 0.f; }
        // rows 1,2 need no halo -> compute first (hides the halo ds_read)
        ROW(1, C[0], C[2]);
        ROW(2, C[1], C[3]);
        ROW(0, nn,   C[1]);
        ROW(3, C[2], ss);
        // source injection BEFORE publish (boundary rows may carry the source)
        if (wave_has_src) {
            const float sv = DT2 * wav[t];
#pragma unroll
            for (int i = 0; i < 4; ++i) {
                if (has_src && si == i) {
                    if      (sj == 0) P[i].x += sv;
                    else if (sj == 1) P[i].y += sv;
                    else if (sj == 2) P[i].z += sv;
                    else              P[i].w += sv;
                }
            }
        }
        // publish level t+1 halo rows, then release progress
        *(v4f*)&pub[nxt][0][band][c0] = P[0];
        *(v4f*)&pub[nxt][1][band][c0] = P[3];
        const int nv = (k == cut && cut < G) ? (t - k + 17)  // dying: t0+16
                                             : (t + 1);
        if (lane == 0)
            __hip_atomic_store(&prog[band], nv, __ATOMIC_RELEASE,
                               __HIP_MEMORY_SCOPE_WORKGROUP);
        // receiver gather (NEW level) -> LDS staging (read at flush barrier)
        if (wave_has_rec) {
#pragma unroll
            for (int kk = 0; kk < RCAP; ++kk) {
                if (rcnt > kk) {
                    int pk = rs[kk];
                    int i = (pk >> 2) & 3, j = pk & 3, r = pk >> 4;
                    v4f t01 = (i & 1) ? P[1] : P[0];
                    v4f t23 = (i & 1) ? P[3] : P[2];
                    v4f rw  = (i & 2) ? t23 : t01;
                    float c01 = (j & 1) ? rw.y : rw.x;
                    float c23 = (j & 1) ? rw.w : rw.z;
                    recbuf[t & (G - 1)][r] = (j & 2) ? c23 : c01;
                }
            }
        }
    };

    // early publish of prev level (Bv is final before the round's last step):
    // its store drain overlaps remaining compute. Interior bands only.
    auto publish_prev = [&](int e) {
        if (band >= 4 && band < 8) {
            int rr0 = (band - 4) << 2;
#pragma unroll
            for (int i = 0; i < 4; ++i)
                store_v4_sys(&gptr(e, blk, 1, rr0 + i)[c0], Bv[i]);
        }
    };

    // exchange after round e. On entry (post-flush-barrier): all bands'
    // prog == t0_new already (live bands reached it; dead bands jumped).
    // s3 == t0_new % 3. Ghost refill then republish level t0_new into pub[s3].
    auto exchange = [&](int e, int s3) {
        if (band >= 4 && band < 8) {       // publish interior, cur level
            int rr0 = (band - 4) << 2;
#pragma unroll
            for (int i = 0; i < 4; ++i)
                store_v4_sys(&gptr(e, blk, 0, rr0 + i)[c0], A[i]);
        }
        __syncthreads();                   // drains each wave's vmcnt first
        if (tid == 0)                      // fire-and-forget; neighbors poll
            __hip_atomic_store(&flags[blk], e + 1, __ATOMIC_RELAXED,
                               __HIP_MEMORY_SCOPE_SYSTEM);
        if (band < 4 && p > 0) {           // top ghost <- north (blk-1) interior
            if (lane == 0)
                while (__hip_atomic_load(&flags[blk - 1], __ATOMIC_RELAXED,
                                         __HIP_MEMORY_SCOPE_SYSTEM) < e + 1)
                    __builtin_amdgcn_s_sleep(1);
            int rr0 = band << 2;           // ext rows 0..15 == slab rows 0..15
#pragma unroll
            for (int i = 0; i < 4; ++i) {
                A[i]  = load_v4_sys(&gptr(e, blk - 1, 0, rr0 + i)[c0]);
                Bv[i] = load_v4_sys(&gptr(e, blk - 1, 1, rr0 + i)[c0]);
            }
        }
        if (band >= 8 && p < PIECES - 1) { // bottom ghost <- south (blk+1)
            if (lane == 0)
                while (__hip_atomic_load(&flags[blk + 1], __ATOMIC_RELAXED,
                                         __HIP_MEMORY_SCOPE_SYSTEM) < e + 1)
                    __builtin_amdgcn_s_sleep(1);
            int rr0 = (band - 8) << 2;     // ext rows 32..47 == slab rows 0..15
#pragma unroll
            for (int i = 0; i < 4; ++i) {
                A[i]  = load_v4_sys(&gptr(e, blk + 1, 0, rr0 + i)[c0]);
                Bv[i] = load_v4_sys(&gptr(e, blk + 1, 1, rr0 + i)[c0]);
            }
        }
        // asm loads are opaque to compiler waitcnt logic (rule #18)
        asm volatile("s_waitcnt vmcnt(0)" ::: "memory");
        __builtin_amdgcn_sched_barrier(0);
        // republish level t0_new into slot s3 (idempotent for interior bands;
        // required for refilled ghosts). Ordered for all by the barrier below.
        *(v4f*)&pub[s3][0][band][c0] = A[0];
        *(v4f*)&pub[s3][1][band][c0] = A[3];
        __syncthreads();
    };

    int t = 0, s3 = 0;
#pragma unroll 1
    for (int e = 0; e < ROUNDS; ++e) {
#pragma unroll 1
        for (int s = 0; s < G; s += 2) {
            step(A, Bv, t, s3);  s3 = (s3 == 2) ? 0 : s3 + 1;
            if (s == G - 2 && e < ROUNDS - 1)
                publish_prev(e);
            step(Bv, A, t + 1, s3); s3 = (s3 == 2) ? 0 : s3 + 1;
            t += 2;
        }
        // flush this round's receiver samples (all waves converge here)
        __syncthreads();
#pragma unroll 1
        for (int idx = tid; idx < G * NREC_; idx += NTHR) {
            int s = idx >> 6, r = idx & 63;
            if (recown[r]) outb[(e * G + s) * NREC_ + r] = recbuf[s][r];
        }
        if (e < ROUNDS - 1) exchange(e, s3);
    }
#undef ROW
}

extern "C" void kernel_launch(void* const* d_in, const int* in_sizes, int n_in,
                              void* d_out, int out_size, void* d_ws, size_t ws_size,
                              hipStream_t stream) {
    const float* x   = (const float*)d_in[0];
    const float* vp  = (const float*)d_in[1];
    const int*   src = (const int*)d_in[2];
    const int*   rec = (const int*)d_in[3];
    float*       o   = (float*)d_out;
    int*   flags = (int*)d_ws;
    float* gbuf  = (float*)((char*)d_ws + FLAGS_BYTES);
    (void)hipMemsetAsync(d_ws, 0, FLAGS_BYTES, stream);   // flags must start at 0
    hipLaunchKernelGGL(wave_reg_kernel, dim3(NBLK), dim3(NTHR), 0, stream,
                       x, vp, src, rec, o, flags, gbuf);
}

// Round 8
// 298.539 us; speedup vs baseline: 1.0007x; 1.0007x over previous
//
#include <hip/hip_runtime.h>

typedef float v4f __attribute__((ext_vector_type(4)));

namespace {
constexpr int B_     = 8;
constexpr int NT_    = 256;
constexpr int NX_    = 256;
constexpr int NREC_  = 64;
constexpr int PIECES = 32;             // R15: 256 blocks -> all 256 CUs
constexpr int IROWS  = 8;              // interior rows per strip
constexpr int G      = 16;             // ghost width = steps per round
constexpr int ROUNDS = NT_ / G;        // 16 (15 exchanges)
constexpr int NB     = (IROWS + 2 * G) / 4;  // bands per block = 10
constexpr int NTHR   = NB * 64;        // 640 threads
constexpr int NBLK   = B_ * PIECES;    // 256 blocks
constexpr float DT2  = 1e-6f;          // DT*DT
constexpr float KLAP = 1e-8f;          // DT*DT/(DH*DH)
constexpr size_t FLAGS_BYTES = 4096;
constexpr int RCAP = 6;
} // namespace

// lane i <- lane i-1 (shfl_up 1). Lane 0 gets 0.0f (bound_ctrl) -- masked by cf=0.
__device__ __forceinline__ float dpp_shr1(float v) {
    return __int_as_float(__builtin_amdgcn_update_dpp(
        0, __float_as_int(v), 0x138 /*WAVE_SHR1*/, 0xF, 0xF, true));
}
// lane i <- lane i+1 (shfl_down 1). Lane 63 gets 0.0f -- masked by cf=0.
__device__ __forceinline__ float dpp_shl1(float v) {
    return __int_as_float(__builtin_amdgcn_update_dpp(
        0, __float_as_int(v), 0x130 /*WAVE_SHL1*/, 0xF, 0xF, true));
}

// R10: fence-free cross-block exchange via sc0 sc1 (system-coherent; bypasses
// the non-coherent per-XCD L2s -- agent fences cost 12-20us/exchange, R9).
// R13: trapezoid band cutoffs (bit-identical, frontier-matched).
// R14 lesson: skew-sync == barrier-sync (the handoff chain is physical, the
// barrier is not the cost) -> keep the simpler barrier step.
// R15: 256 blocks (PIECES=32, IROWS=8), G=16 kept -> ghost (16 rows) spans TWO
// neighbor interiors -> two-hop exchange: bands 0-1 <- blk-2, 2-3 <- blk-1,
// 6-7 <- blk+1, 8-9 <- blk+2 (each guarded; out-of-domain bands hold exact
// zeros since cf=0 rows never leave 0). Trapezoid for NB=10:
// cut = 4b+3 | 16 | 39-4b. Equiv bands 6.5 vs R13's 8.5 on 2x CUs.
__device__ __forceinline__ void store_v4_sys(float* p, v4f v) {
    asm volatile("global_store_dwordx4 %0, %1, off sc0 sc1"
                 :: "v"(p), "v"(v) : "memory");
}
__device__ __forceinline__ v4f load_v4_sys(const float* p) {
    v4f r;
    asm volatile("global_load_dwordx4 %0, %1, off sc0 sc1"
                 : "=v"(r) : "v"(p) : "memory");
    return r;
}

extern "C" __global__
__attribute__((amdgpu_flat_work_group_size(NTHR, NTHR), amdgpu_waves_per_eu(4, 4)))
void wave_reg_kernel(const float* __restrict__ x,
                     const float* __restrict__ vp,
                     const int* __restrict__ src_loc,
                     const int* __restrict__ rec_loc,
                     float* __restrict__ out,
                     int* __restrict__ flags,   // [256] monotone round counters
                     float* __restrict__ gbuf)  // [par2][256][lvl2][8][256]
{
    __shared__ float pub[2][2][NB][256];   // 40 KB: [par][top/bot row][band][col]
    __shared__ float wav[NT_];             // 1 KB wavelet
    __shared__ float recbuf[G][NREC_];     // 4 KB receiver staging (per round)
    __shared__ unsigned char recown[NREC_];// per-rec ownership of this block

    const int bid  = blockIdx.x;
    const int b    = bid & 7;
    const int p    = bid >> 3;             // 0..31
    const int blk  = b * PIECES + p;
    const int tid  = threadIdx.x;
    const int band = tid >> 6;             // wave id 0..9 -> 4 ext rows
    const int lane = tid & 63;
    const int c0   = lane << 2;            // first owned col (0..252)
    const int grt  = p * IROWS - G + (band << 2);  // global row of owned row 0

    // trapezoid cutoff: compute in-round step k (1-based) iff k<=cut;
    // publish iff k<=cut+1. Frontier-matched (R13 proof) -> bit-identical.
    const int cut = (band < 4) ? ((band << 2) + 3)
                  : ((band < 6) ? G : (39 - (band << 2)));

    if (tid < NT_) wav[tid] = x[b * NT_ + tid];
    if (tid < NREC_) {
        int rz = rec_loc[(b * NREC_ + tid) * 2 + 0];
        recown[tid] = (rz >= p * IROWS && rz < p * IROWS + IROWS) ? 1 : 0;
    }

    // cf = vp^2*DT^2/DH^2, zeroed at Dirichlet boundary + out-of-domain rows.
    // cf2 = 2 - 4*cf: hn = cf*((N+S)+(E+W)) + (cf2*C - P)
    v4f cf[4], cf2[4];
#pragma unroll
    for (int i = 0; i < 4; ++i) {
        int gr = grt + i;
        int crow = gr < 0 ? 0 : (gr > 255 ? 255 : gr);
        bool rowok = (gr >= 1) && (gr <= 254);
        v4f vv = *(const v4f*)&vp[crow * NX_ + c0];
        float cc[4];
#pragma unroll
        for (int k = 0; k < 4; ++k) {
            int col = c0 + k;
            float vk = (k == 0) ? vv.x : (k == 1) ? vv.y : (k == 2) ? vv.z : vv.w;
            cc[k] = (rowok && col >= 1 && col <= 254) ? vk * vk * KLAP : 0.f;
        }
        cf[i].x = cc[0]; cf[i].y = cc[1]; cf[i].z = cc[2]; cf[i].w = cc[3];
        cf2[i].x = 2.f - 4.f * cc[0]; cf2[i].y = 2.f - 4.f * cc[1];
        cf2[i].z = 2.f - 4.f * cc[2]; cf2[i].w = 2.f - 4.f * cc[3];
    }

    // source ownership (ghost rows included: ghost evolution must replay it)
    const int sz = src_loc[b * 2 + 0], sx = src_loc[b * 2 + 1];
    const int si = sz - grt;               // 0..3 if owned row
    const int sj = sx - c0;                // 0..3 if owned col
    const bool has_src = ((unsigned)si < 4u) && ((unsigned)sj < 4u);
    const bool wave_has_src = __any(has_src);

    // receiver slots: interior owner only (unique writer). pk=(r<<4)|(i<<2)|j
    int rs[RCAP]; int rcnt = 0;
#pragma unroll 1
    for (int r = 0; r < NREC_; ++r) {
        int rz = rec_loc[(b * NREC_ + r) * 2 + 0];
        int rx = rec_loc[(b * NREC_ + r) * 2 + 1];
        int i = rz - grt, j = rx - c0;
        if (rz >= p * IROWS && rz < p * IROWS + IROWS &&
            (unsigned)i < 4u && (unsigned)j < 4u) {
            if (rcnt < RCAP) rs[rcnt] = (r << 4) | (i << 2) | j;
            ++rcnt;
        }
    }
    if (rcnt > RCAP) rcnt = RCAP;
    const bool wave_has_rec = __any(rcnt > 0);
    float* outb = out + (size_t)b * NT_ * NREC_;

    v4f A[4], Bv[4];
    {
        v4f z = {0.f, 0.f, 0.f, 0.f};
#pragma unroll
        for (int i = 0; i < 4; ++i) { A[i] = z; Bv[i] = z; }
    }

    // gbuf slab pointer: [par][blk][lvl][row(0..7)][col]; interior = the slab.
    auto gptr = [&](int e, int bk, int lvl, int rr) -> float* {
        return gbuf + ((((size_t)(e & 1) * NBLK + bk) * 2 + lvl) * 8 + rr) * 256;
    };

    // one step: P <- update(C, P); P becomes current. par = t&1. (R13 form)
    auto step = [&](v4f (&C)[4], v4f (&P)[4], int t, int par) {
        const int k = (t & (G - 1)) + 1;
        if (k <= cut + 1) {                 // publish window = compute window +1
            *(v4f*)&pub[par][0][band][c0] = C[0];  // top row (S halo of band-1)
            *(v4f*)&pub[par][1][band][c0] = C[3];  // bottom row (N halo of band+1)
        }
        __syncthreads();
        if (k > cut) return;                // all this band's rows are dead now
        v4f nn, ss;
        if (band > 0)      nn = *(const v4f*)&pub[par][1][band - 1][c0];
        else               { nn.x = 0.f; nn.y = 0.f; nn.z = 0.f; nn.w = 0.f; }
        if (band < NB - 1) ss = *(const v4f*)&pub[par][0][band + 1][c0];
        else               { ss.x = 0.f; ss.y = 0.f; ss.z = 0.f; ss.w = 0.f; }
#pragma unroll
        for (int i = 0; i < 4; ++i) {
            v4f n = (i == 0) ? nn : C[i - 1];
            v4f s = (i == 3) ? ss : C[i + 1];
            float wv = dpp_shr1(C[i].w);   // col c0-1 (lane0 -> 0: cf=0 masks)
            float ev = dpp_shl1(C[i].x);   // col c0+4 (lane63 -> 0: cf=0 masks)
            v4f hn;
            { float sm = (n.x + s.x) + (wv     + C[i].y);
              hn.x = fmaf(cf[i].x, sm, fmaf(cf2[i].x, C[i].x, -P[i].x)); }
            { float sm = (n.y + s.y) + (C[i].x + C[i].z);
              hn.y = fmaf(cf[i].y, sm, fmaf(cf2[i].y, C[i].y, -P[i].y)); }
            { float sm = (n.z + s.z) + (C[i].y + C[i].w);
              hn.z = fmaf(cf[i].z, sm, fmaf(cf2[i].z, C[i].z, -P[i].z)); }
            { float sm = (n.w + s.w) + (C[i].z + ev);
              hn.w = fmaf(cf[i].w, sm, fmaf(cf2[i].w, C[i].w, -P[i].w)); }
            P[i] = hn;
        }
        if (wave_has_src) {
            const float sv = DT2 * wav[t];
#pragma unroll
            for (int i = 0; i < 4; ++i) {
                if (has_src && si == i) {
                    if      (sj == 0) P[i].x += sv;
                    else if (sj == 1) P[i].y += sv;
                    else if (sj == 2) P[i].z += sv;
                    else              P[i].w += sv;
                }
            }
        }
        if (wave_has_rec) {
#pragma unroll
            for (int kk = 0; kk < RCAP; ++kk) {
                if (rcnt > kk) {
                    int pk = rs[kk];
                    int i = (pk >> 2) & 3, j = pk & 3, r = pk >> 4;
                    v4f t01 = (i & 1) ? P[1] : P[0];
                    v4f t23 = (i & 1) ? P[3] : P[2];
                    v4f rw  = (i & 2) ? t23 : t01;
                    float c01 = (j & 1) ? rw.y : rw.x;
                    float c23 = (j & 1) ? rw.w : rw.z;
                    recbuf[t & (G - 1)][r] = (j & 2) ? c23 : c01;
                }
            }
        }
        // no trailing barrier: next step uses pub[par^1] (parity double-buffer)
    };

    // early publish of prev level (Bv final before the round's last step):
    // store drain overlaps the final step. Interior bands 4,5 only.
    auto publish_prev = [&](int e) {
        if (band == 4 || band == 5) {
            int rr0 = (band - 4) << 2;
#pragma unroll
            for (int i = 0; i < 4; ++i)
                store_v4_sys(&gptr(e, blk, 1, rr0 + i)[c0], Bv[i]);
        }
    };

    // two-hop exchange after round e: publish interior (cur), drain via the
    // barrier's vmcnt(0), flag (fire-and-forget), ghost waves poll the flag of
    // THEIR source block (+-1 or +-2) and refill.
    auto exchange = [&](int e) {
        if (band == 4 || band == 5) {      // publish interior, cur level
            int rr0 = (band - 4) << 2;
#pragma unroll
            for (int i = 0; i < 4; ++i)
                store_v4_sys(&gptr(e, blk, 0, rr0 + i)[c0], A[i]);
        }
        __syncthreads();                   // drains each wave's vmcnt first
        if (tid == 0)                      // fire-and-forget; neighbors poll
            __hip_atomic_store(&flags[blk], e + 1, __ATOMIC_RELAXED,
                               __HIP_MEMORY_SCOPE_SYSTEM);
        // wave-level poll: lane0 loop holds the whole wave's PC, so the
        // subsequent loads cannot issue before the flag trips.
        if (band < 2 && p >= 2) {          // ext rows 0..7  <- blk-2 interior
            if (lane == 0)
                while (__hip_atomic_load(&flags[blk - 2], __ATOMIC_RELAXED,
                                         __HIP_MEMORY_SCOPE_SYSTEM) < e + 1)
                    __builtin_amdgcn_s_sleep(1);
            int rr0 = band << 2;
#pragma unroll
            for (int i = 0; i < 4; ++i) {
                A[i]  = load_v4_sys(&gptr(e, blk - 2, 0, rr0 + i)[c0]);
                Bv[i] = load_v4_sys(&gptr(e, blk - 2, 1, rr0 + i)[c0]);
            }
        }
        if (band >= 2 && band < 4 && p >= 1) {  // ext rows 8..15 <- blk-1
            if (lane == 0)
                while (__hip_atomic_load(&flags[blk - 1], __ATOMIC_RELAXED,
                                         __HIP_MEMORY_SCOPE_SYSTEM) < e + 1)
                    __builtin_amdgcn_s_sleep(1);
            int rr0 = (band - 2) << 2;
#pragma unroll
            for (int i = 0; i < 4; ++i) {
                A[i]  = load_v4_sys(&gptr(e, blk - 1, 0, rr0 + i)[c0]);
                Bv[i] = load_v4_sys(&gptr(e, blk - 1, 1, rr0 + i)[c0]);
            }
        }
        if (band >= 6 && band < 8 && p < PIECES - 1) {  // ext 24..31 <- blk+1
            if (lane == 0)
                while (__hip_atomic_load(&flags[blk + 1], __ATOMIC_RELAXED,
                                         __HIP_MEMORY_SCOPE_SYSTEM) < e + 1)
                    __builtin_amdgcn_s_sleep(1);
            int rr0 = (band - 6) << 2;
#pragma unroll
            for (int i = 0; i < 4; ++i) {
                A[i]  = load_v4_sys(&gptr(e, blk + 1, 0, rr0 + i)[c0]);
                Bv[i] = load_v4_sys(&gptr(e, blk + 1, 1, rr0 + i)[c0]);
            }
        }
        if (band >= 8 && p < PIECES - 2) {  // ext rows 32..39 <- blk+2
            if (lane == 0)
                while (__hip_atomic_load(&flags[blk + 2], __ATOMIC_RELAXED,
                                         __HIP_MEMORY_SCOPE_SYSTEM) < e + 1)
                    __builtin_amdgcn_s_sleep(1);
            int rr0 = (band - 8) << 2;
#pragma unroll
            for (int i = 0; i < 4; ++i) {
                A[i]  = load_v4_sys(&gptr(e, blk + 2, 0, rr0 + i)[c0]);
                Bv[i] = load_v4_sys(&gptr(e, blk + 2, 1, rr0 + i)[c0]);
            }
        }
        // asm loads are opaque to compiler waitcnt logic (rule #18)
        asm volatile("s_waitcnt vmcnt(0)" ::: "memory");
        __builtin_amdgcn_sched_barrier(0);
        __syncthreads();                   // all waves aligned for next round
    };

    int t = 0;
#pragma unroll 1
    for (int e = 0; e < ROUNDS; ++e) {
#pragma unroll 1
        for (int s = 0; s < G; s += 2) {
            step(A, Bv, t, 0);      // t even: cur=A, par=0
            if (s == G - 2 && e < ROUNDS - 1)
                publish_prev(e);    // Bv = lvl t_end-1 is final; overlap drain
            step(Bv, A, t + 1, 1);  // t odd:  cur=B, par=1
            t += 2;
        }
        // flush this round's receiver samples (G*NREC=1024 slots, 640 threads)
        __syncthreads();           // recbuf writes came from scattered owners
#pragma unroll 1
        for (int idx = tid; idx < G * NREC_; idx += NTHR) {
            int s = idx >> 6, r = idx & 63;
            if (recown[r]) outb[(e * G + s) * NREC_ + r] = recbuf[s][r];
        }
        if (e < ROUNDS - 1) exchange(e);
    }
}

extern "C" void kernel_launch(void* const* d_in, const int* in_sizes, int n_in,
                              void* d_out, int out_size, void* d_ws, size_t ws_size,
                              hipStream_t stream) {
    const float* x   = (const float*)d_in[0];
    const float* vp  = (const float*)d_in[1];
    const int*   src = (const int*)d_in[2];
    const int*   rec = (const int*)d_in[3];
    float*       o   = (float*)d_out;
    int*   flags = (int*)d_ws;
    float* gbuf  = (float*)((char*)d_ws + FLAGS_BYTES);
    (void)hipMemsetAsync(d_ws, 0, FLAGS_BYTES, stream);   // flags must start at 0
    hipLaunchKernelGGL(wave_reg_kernel, dim3(NBLK), dim3(NTHR), 0, stream,
                       x, vp, src, rec, o, flags, gbuf);
}